// Round 1
// baseline (194.133 us; speedup 1.0000x reference)
//
#include <hip/hip_runtime.h>

#define N_ATOMS 131072
#define N_TYPES 256
#define D 64
#define CAP 1024   // per-type bucket capacity; counts ~Binomial(131072,1/256): mean 512, std 22.6 -> 22 sigma margin
#define BPT 2      // blocks per type in apply kernel

// ---------------------------------------------------------------------------
// Pass 1: counting-sort atoms by type into fixed-capacity buckets.
// LDS-aggregated: per-block histogram, one global atomicAdd per nonzero bin,
// then local scatter. 256 blocks x 256 threads, 512 atoms per block.
// ---------------------------------------------------------------------------
__global__ __launch_bounds__(256) void scatter_kernel(
    const int* __restrict__ types, int* __restrict__ cursor, int* __restrict__ bucket)
{
    __shared__ int lhist[N_TYPES];
    __shared__ int lbase[N_TYPES];
    __shared__ int lcur[N_TYPES];
    const int tid = threadIdx.x;
    lhist[tid] = 0;
    __syncthreads();

    const int a0 = blockIdx.x * 512 + tid;
    const int a1 = a0 + 256;
    const int t0 = types[a0];
    const int t1 = types[a1];
    atomicAdd(&lhist[t0], 1);
    atomicAdd(&lhist[t1], 1);
    __syncthreads();

    const int cnt = lhist[tid];
    if (cnt > 0) lbase[tid] = atomicAdd(&cursor[tid], cnt);
    lcur[tid] = 0;
    __syncthreads();

    int p0 = atomicAdd(&lcur[t0], 1);
    int q0 = lbase[t0] + p0;
    if (q0 < CAP) bucket[t0 * CAP + q0] = a0;
    int p1 = atomicAdd(&lcur[t1], 1);
    int q1 = lbase[t1] + p1;
    if (q1 < CAP) bucket[t1 * CAP + q1] = a1;
}

// ---------------------------------------------------------------------------
// Pass 2: per-type apply. blockIdx.y = type (uniform) -> W[t]/b[t] accesses
// are wave-uniform and should compile to s_load (SMEM pipe), broadcast free.
// Lane = atom: x-row (64 fp32) lives in VGPRs; 16 outputs accumulated per
// o-chunk; fp32 exact compute; fast tanh via exp.
// ---------------------------------------------------------------------------
__device__ __forceinline__ float fast_tanh(float v)
{
    // tanh(v) = 1 - 2/(exp(2v)+1); exact at +/-inf behavior via rcp(inf)=0.
    float e = __expf(2.0f * v);
    return 1.0f - __fdividef(2.0f, e + 1.0f);
}

__global__ __launch_bounds__(256, 2) void apply_kernel(
    const float* __restrict__ x, const float* __restrict__ W,
    const float* __restrict__ b, const int* __restrict__ bucket,
    const int* __restrict__ cursor, float* __restrict__ out)
{
    const int t = blockIdx.y;          // type: uniform across block
    const int j = blockIdx.x;          // 0..BPT-1
    int n = cursor[t];
    if (n > CAP) n = CAP;

    const int wave = threadIdx.x >> 6;
    const int lane = threadIdx.x & 63;
    const float* Wt = W + (size_t)t * (D * D);
    const float* bt = b + (size_t)t * D;
    const int*   bk = bucket + (size_t)t * CAP;

    // wave handles 64-atom chunks: c = j*4 + wave, stride BPT*4 = 8
    for (int c = j * 4 + wave; c * 64 < n; c += BPT * 4) {
        const int r = c * 64 + lane;
        const bool valid = (r < n);
        const int atom = bk[valid ? r : 0];

        // load this lane's x row into registers (16 x dwordx4, per-lane contiguous)
        const float4* xr = (const float4*)(x + (size_t)atom * D);
        float xv[D];
#pragma unroll
        for (int i = 0; i < 16; ++i) {
            float4 v = xr[i];
            xv[4 * i + 0] = v.x;
            xv[4 * i + 1] = v.y;
            xv[4 * i + 2] = v.z;
            xv[4 * i + 3] = v.w;
        }

        float4* yr = (float4*)(out + (size_t)atom * D);

#pragma unroll 1
        for (int oc = 0; oc < 4; ++oc) {   // 4 chunks of 16 outputs
            float acc[16];
#pragma unroll
            for (int oo = 0; oo < 16; ++oo) acc[oo] = bt[oc * 16 + oo];

#pragma unroll
            for (int oo = 0; oo < 16; ++oo) {
                const float* wr = Wt + (size_t)(oc * 16 + oo) * D;
#pragma unroll
                for (int i = 0; i < D; ++i)
                    acc[oo] = fmaf(wr[i], xv[i], acc[oo]);   // v_fmac with sgpr W operand
            }

            if (valid) {
#pragma unroll
                for (int q = 0; q < 4; ++q) {
                    float4 o4;
                    o4.x = fast_tanh(acc[4 * q + 0]);
                    o4.y = fast_tanh(acc[4 * q + 1]);
                    o4.z = fast_tanh(acc[4 * q + 2]);
                    o4.w = fast_tanh(acc[4 * q + 3]);
                    yr[oc * 4 + q] = o4;
                }
            }
        }
    }
}

extern "C" void kernel_launch(void* const* d_in, const int* in_sizes, int n_in,
                              void* d_out, int out_size, void* d_ws, size_t ws_size,
                              hipStream_t stream)
{
    const float* x     = (const float*)d_in[0];
    const int*   types = (const int*)  d_in[1];
    const float* W     = (const float*)d_in[2];
    const float* b     = (const float*)d_in[3];
    float*       out   = (float*)d_out;

    // ws layout: [0,1KB) cursor int[256]; [1KB, 1KB+1MB) bucket int[256*1024]
    int* cursor = (int*)d_ws;
    int* bucket = (int*)((char*)d_ws + 1024);

    hipMemsetAsync(cursor, 0, N_TYPES * sizeof(int), stream);
    scatter_kernel<<<dim3(N_ATOMS / 512), dim3(256), 0, stream>>>(types, cursor, bucket);
    apply_kernel<<<dim3(BPT, N_TYPES), dim3(256), 0, stream>>>(x, W, b, bucket, cursor, out);
}